// Round 15
// baseline (409.084 us; speedup 1.0000x reference)
//
#include <hip/hip_runtime.h>
#include <math.h>
#include <stdint.h>

// ---- problem constants ----
#define T_    2048
#define D_    4096
#define NH_   32
#define QL_   1536     // Q_LORA
#define KVL_  512      // KV_LORA
#define ROPE_ 64       // QK_ROPE
#define NOPE_ 128      // QK_NOPE
#define HQK_  192      // QK_HEAD
#define HV_   128      // V_HEAD
#define KVD_  576      // KV_LORA + QK_ROPE
#define NCAT_ 2112     // QL_ + KVD_ (fused down-projection width)

typedef __bf16 bf16x8 __attribute__((ext_vector_type(8)));
typedef __bf16 bf16x4 __attribute__((ext_vector_type(4)));
typedef float f32x4 __attribute__((ext_vector_type(4)));

// async global->LDS, 16B per lane. LDS dest = wave-uniform base + lane*16.
__device__ __forceinline__ void gload_lds16(const __bf16* g, __bf16* l) {
  __builtin_amdgcn_global_load_lds(
      (const __attribute__((address_space(1))) void*)g,
      (__attribute__((address_space(3))) void*)l, 16, 0, 0);
}

// ============ bf16 MFMA GEMM (m97 structure): C[M][N] = A[M][K] * Bt[N][K]^T ====
// 128x128 tile, BK=64, 256 thr = 4 waves (2x2), each wave 64x64 = 4x4 frags.
template <typename OutT>
__global__ __launch_bounds__(256, 3) void mfma_gemm_kernel(
    const __bf16* __restrict__ A, const __bf16* __restrict__ Bt,
    OutT* __restrict__ C, int M, int Ncols, int K) {
  __shared__ __bf16 As[128 * 64];   // 16 KB
  __shared__ __bf16 Bs[128 * 64];   // 16 KB
  const int tid = threadIdx.x;
  const int lane = tid & 63;
  const int w = tid >> 6;
  const int wm = w >> 1, wn = w & 1;
  const int lg = lane >> 4, lj = lane & 15;
  const int bm = blockIdx.y * 128;
  const int bn = blockIdx.x * 128;

  const __bf16* ga[4]; const __bf16* gb[4];
  int ldsoff[4];
  #pragma unroll
  for (int i = 0; i < 4; ++i) {
    int task = i * 256 + tid;
    int r = task >> 3, cl = task & 7;
    int cg = cl ^ (r & 7);
    ga[i] = A  + (size_t)(bm + r) * K + cg * 8;
    gb[i] = Bt + (size_t)(bn + r) * K + cg * 8;
    ldsoff[i] = (i * 256 + w * 64) * 8;
  }

  f32x4 acc[4][4];
  #pragma unroll
  for (int mi = 0; mi < 4; ++mi)
    #pragma unroll
    for (int ni = 0; ni < 4; ++ni) acc[mi][ni] = (f32x4){0.f, 0.f, 0.f, 0.f};

  for (int k0 = 0; k0 < K; k0 += 64) {
    __syncthreads();
    #pragma unroll
    for (int i = 0; i < 4; ++i) gload_lds16(ga[i] + k0, &As[ldsoff[i]]);
    #pragma unroll
    for (int i = 0; i < 4; ++i) gload_lds16(gb[i] + k0, &Bs[ldsoff[i]]);
    __syncthreads();
    #pragma unroll
    for (int kh = 0; kh < 2; ++kh) {
      bf16x8 af[4], bfr[4];
      #pragma unroll
      for (int i = 0; i < 4; ++i) {
        int ra = wm * 64 + i * 16 + lj;
        af[i] = *(const bf16x8*)&As[ra * 64 + ((((kh << 2) + lg) ^ (ra & 7)) << 3)];
      }
      #pragma unroll
      for (int i = 0; i < 4; ++i) {
        int rb = wn * 64 + i * 16 + lj;
        bfr[i] = *(const bf16x8*)&Bs[rb * 64 + ((((kh << 2) + lg) ^ (rb & 7)) << 3)];
      }
      #pragma unroll
      for (int mi = 0; mi < 4; ++mi)
        #pragma unroll
        for (int ni = 0; ni < 4; ++ni)
          acc[mi][ni] = __builtin_amdgcn_mfma_f32_16x16x32_bf16(af[mi], bfr[ni], acc[mi][ni], 0, 0, 0);
    }
  }

  #pragma unroll
  for (int mi = 0; mi < 4; ++mi) {
    #pragma unroll
    for (int r = 0; r < 4; ++r) {
      int row = bm + wm * 64 + mi * 16 + lg * 4 + r;
      #pragma unroll
      for (int ni = 0; ni < 4; ++ni) {
        int col = bn + wn * 64 + ni * 16 + lj;
        if (col < Ncols) C[(size_t)row * Ncols + col] = (OutT)acc[mi][ni][r];
      }
    }
  }
}

// ============ q_up GEMM with FUSED ROPE epilogue ============
// N = NH*HQK = 6144. A 64-wide wave-tile is a head's rope block iff
// (col0 % 192) == 128 (wave-uniform). Rope pair (i, i+32) = acc[.][ni] vs
// acc[.][ni+2], rotated in fp32 before the bf16 store. Kills rope_q kernel.
__global__ __launch_bounds__(256, 3) void qup_gemm_kernel(
    const __bf16* __restrict__ A, const __bf16* __restrict__ Bt,
    __bf16* __restrict__ C, const float* __restrict__ cosT,
    const float* __restrict__ sinT, int M, int Ncols, int K) {
  __shared__ __bf16 As[128 * 64];
  __shared__ __bf16 Bs[128 * 64];
  const int tid = threadIdx.x;
  const int lane = tid & 63;
  const int w = tid >> 6;
  const int wm = w >> 1, wn = w & 1;
  const int lg = lane >> 4, lj = lane & 15;
  const int bm = blockIdx.y * 128;
  const int bn = blockIdx.x * 128;

  const __bf16* ga[4]; const __bf16* gb[4];
  int ldsoff[4];
  #pragma unroll
  for (int i = 0; i < 4; ++i) {
    int task = i * 256 + tid;
    int r = task >> 3, cl = task & 7;
    int cg = cl ^ (r & 7);
    ga[i] = A  + (size_t)(bm + r) * K + cg * 8;
    gb[i] = Bt + (size_t)(bn + r) * K + cg * 8;
    ldsoff[i] = (i * 256 + w * 64) * 8;
  }

  f32x4 acc[4][4];
  #pragma unroll
  for (int mi = 0; mi < 4; ++mi)
    #pragma unroll
    for (int ni = 0; ni < 4; ++ni) acc[mi][ni] = (f32x4){0.f, 0.f, 0.f, 0.f};

  for (int k0 = 0; k0 < K; k0 += 64) {
    __syncthreads();
    #pragma unroll
    for (int i = 0; i < 4; ++i) gload_lds16(ga[i] + k0, &As[ldsoff[i]]);
    #pragma unroll
    for (int i = 0; i < 4; ++i) gload_lds16(gb[i] + k0, &Bs[ldsoff[i]]);
    __syncthreads();
    #pragma unroll
    for (int kh = 0; kh < 2; ++kh) {
      bf16x8 af[4], bfr[4];
      #pragma unroll
      for (int i = 0; i < 4; ++i) {
        int ra = wm * 64 + i * 16 + lj;
        af[i] = *(const bf16x8*)&As[ra * 64 + ((((kh << 2) + lg) ^ (ra & 7)) << 3)];
      }
      #pragma unroll
      for (int i = 0; i < 4; ++i) {
        int rb = wn * 64 + i * 16 + lj;
        bfr[i] = *(const bf16x8*)&Bs[rb * 64 + ((((kh << 2) + lg) ^ (rb & 7)) << 3)];
      }
      #pragma unroll
      for (int mi = 0; mi < 4; ++mi)
        #pragma unroll
        for (int ni = 0; ni < 4; ++ni)
          acc[mi][ni] = __builtin_amdgcn_mfma_f32_16x16x32_bf16(af[mi], bfr[ni], acc[mi][ni], 0, 0, 0);
    }
  }

  const bool isrope = (((bn + wn * 64) % HQK_) == NOPE_);   // wave-uniform
  #pragma unroll
  for (int mi = 0; mi < 4; ++mi) {
    #pragma unroll
    for (int r = 0; r < 4; ++r) {
      int row = bm + wm * 64 + mi * 16 + lg * 4 + r;
      if (isrope) {
        #pragma unroll
        for (int ni = 0; ni < 2; ++ni) {
          int i = ni * 16 + lj;                 // 0..31
          float c = cosT[row * 32 + i];
          float s = sinT[row * 32 + i];
          float x1 = acc[mi][ni][r], x2 = acc[mi][ni + 2][r];
          acc[mi][ni][r]     = x1 * c - x2 * s;
          acc[mi][ni + 2][r] = x1 * s + x2 * c;
        }
      }
      #pragma unroll
      for (int ni = 0; ni < 4; ++ni) {
        int col = bn + wn * 64 + ni * 16 + lj;
        C[(size_t)row * Ncols + col] = (__bf16)acc[mi][ni][r];
      }
    }
  }
}

// ============ down-projection GEMM, BK=128, fp32-A (no conv pass) ============
// A = x [T][4096] fp32, reg-staged + converted inline; B bf16 via global_load_lds.
// 272 blocks ~1/CU: BK=128 halves exposed barrier drains.
__global__ __launch_bounds__(256, 2) void downproj_gemm_kernel(
    const float* __restrict__ A, const __bf16* __restrict__ Bt,
    __bf16* __restrict__ C, int M, int Ncols, int K) {
  __shared__ __bf16 As[128 * 128];   // 32 KB
  __shared__ __bf16 Bs[128 * 128];   // 32 KB
  const int tid = threadIdx.x;
  const int lane = tid & 63;
  const int w = tid >> 6;
  const int wm = w >> 1, wn = w & 1;
  const int lg = lane >> 4, lj = lane & 15;
  const int bm = blockIdx.y * 128;
  const int bn = blockIdx.x * 128;

  // A: 2048 slot-tasks (128 rows x 16 slots), 8 rounds; fp32 load + convert.
  const float* gaf[8]; int aslot[8];
  // B: 2048 chunk-tasks via global_load_lds
  const __bf16* gb[8]; int ldsoff[8];
  #pragma unroll
  for (int i = 0; i < 8; ++i) {
    int task = i * 256 + tid;
    int r = task >> 4, cl = task & 15;
    int cg = (cl & 8) | ((cl & 7) ^ (r & 7));
    gaf[i] = A + (size_t)(bm + r) * K + cg * 8;
    aslot[i] = r * 128 + cl * 8;
    gb[i] = Bt + (size_t)(bn + r) * K + cg * 8;
    ldsoff[i] = (i * 256 + w * 64) * 8;
  }

  f32x4 acc[4][4];
  #pragma unroll
  for (int mi = 0; mi < 4; ++mi)
    #pragma unroll
    for (int ni = 0; ni < 4; ++ni) acc[mi][ni] = (f32x4){0.f, 0.f, 0.f, 0.f};

  for (int k0 = 0; k0 < K; k0 += 128) {
    // preload A fp32 into regs before barrier (overlaps previous compute tail)
    float4 av0[8], av1[8];
    #pragma unroll
    for (int i = 0; i < 8; ++i) {
      av0[i] = *(const float4*)(gaf[i] + k0);
      av1[i] = *(const float4*)(gaf[i] + k0 + 4);
    }
    __syncthreads();
    #pragma unroll
    for (int i = 0; i < 8; ++i) {
      bf16x8 v;
      v[0] = (__bf16)av0[i].x; v[1] = (__bf16)av0[i].y;
      v[2] = (__bf16)av0[i].z; v[3] = (__bf16)av0[i].w;
      v[4] = (__bf16)av1[i].x; v[5] = (__bf16)av1[i].y;
      v[6] = (__bf16)av1[i].z; v[7] = (__bf16)av1[i].w;
      *(bf16x8*)&As[aslot[i]] = v;
    }
    #pragma unroll
    for (int i = 0; i < 8; ++i) gload_lds16(gb[i] + k0, &Bs[ldsoff[i]]);
    __syncthreads();
    #pragma unroll
    for (int kh = 0; kh < 4; ++kh) {
      bf16x8 af[4], bfr[4];
      #pragma unroll
      for (int i = 0; i < 4; ++i) {
        int ra = wm * 64 + i * 16 + lj;
        int kc = (kh << 2) + lg;
        int slot = (kc & 8) | ((kc & 7) ^ (ra & 7));
        af[i] = *(const bf16x8*)&As[ra * 128 + (slot << 3)];
      }
      #pragma unroll
      for (int i = 0; i < 4; ++i) {
        int rb = wn * 64 + i * 16 + lj;
        int kc = (kh << 2) + lg;
        int slot = (kc & 8) | ((kc & 7) ^ (rb & 7));
        bfr[i] = *(const bf16x8*)&Bs[rb * 128 + (slot << 3)];
      }
      #pragma unroll
      for (int mi = 0; mi < 4; ++mi)
        #pragma unroll
        for (int ni = 0; ni < 4; ++ni)
          acc[mi][ni] = __builtin_amdgcn_mfma_f32_16x16x32_bf16(af[mi], bfr[ni], acc[mi][ni], 0, 0, 0);
    }
  }

  #pragma unroll
  for (int mi = 0; mi < 4; ++mi) {
    #pragma unroll
    for (int r = 0; r < 4; ++r) {
      int row = bm + wm * 64 + mi * 16 + lg * 4 + r;
      #pragma unroll
      for (int ni = 0; ni < 4; ++ni) {
        int col = bn + wn * 64 + ni * 16 + lj;
        if (col < Ncols) C[(size_t)row * Ncols + col] = (__bf16)acc[mi][ni][r];
      }
    }
  }
}

// ============ kv_up GEMM with fused V-transpose output ============
__global__ __launch_bounds__(256, 3) void kvup_gemm_kernel(
    const __bf16* __restrict__ A /*kv_latb [T][512]*/,
    const __bf16* __restrict__ Bt /*Bt_kvu [8192][512]*/,
    __bf16* __restrict__ kv_nopeb /*[T][NH][256]*/,
    __bf16* __restrict__ Vt /*[NH][HV][T]*/) {
  __shared__ __bf16 As[128 * 64];
  __shared__ __bf16 Bs[128 * 64];
  const int tid = threadIdx.x;
  const int lane = tid & 63;
  const int w = tid >> 6;
  const int wm = w >> 1, wn = w & 1;
  const int lg = lane >> 4, lj = lane & 15;
  const int bm = blockIdx.y * 128;          // token rows
  const int bn = blockIdx.x * 128;          // Bt rows (flattened n*256 + j)
  const int n = blockIdx.x >> 1;
  const bool vhalf = (blockIdx.x & 1) != 0;
  const int K = KVL_;

  const __bf16* ga[4]; const __bf16* gb[4];
  int ldsoff[4];
  #pragma unroll
  for (int i = 0; i < 4; ++i) {
    int task = i * 256 + tid;
    int r = task >> 3, cl = task & 7;
    int cg = cl ^ (r & 7);
    ga[i] = A  + (size_t)(bm + r) * K + cg * 8;
    gb[i] = Bt + (size_t)(bn + r) * K + cg * 8;
    ldsoff[i] = (i * 256 + w * 64) * 8;
  }

  const __bf16* RowT = vhalf ? &Bs[0] : &As[0];
  const __bf16* ColT = vhalf ? &As[0] : &Bs[0];

  f32x4 acc[4][4];
  #pragma unroll
  for (int mi = 0; mi < 4; ++mi)
    #pragma unroll
    for (int ni = 0; ni < 4; ++ni) acc[mi][ni] = (f32x4){0.f, 0.f, 0.f, 0.f};

  for (int k0 = 0; k0 < K; k0 += 64) {
    __syncthreads();
    #pragma unroll
    for (int i = 0; i < 4; ++i) gload_lds16(ga[i] + k0, &As[ldsoff[i]]);
    #pragma unroll
    for (int i = 0; i < 4; ++i) gload_lds16(gb[i] + k0, &Bs[ldsoff[i]]);
    __syncthreads();
    #pragma unroll
    for (int kh = 0; kh < 2; ++kh) {
      bf16x8 af[4], bfr[4];
      #pragma unroll
      for (int i = 0; i < 4; ++i) {
        int ra = wm * 64 + i * 16 + lj;
        af[i] = *(const bf16x8*)&RowT[ra * 64 + ((((kh << 2) + lg) ^ (ra & 7)) << 3)];
      }
      #pragma unroll
      for (int i = 0; i < 4; ++i) {
        int rb = wn * 64 + i * 16 + lj;
        bfr[i] = *(const bf16x8*)&ColT[rb * 64 + ((((kh << 2) + lg) ^ (rb & 7)) << 3)];
      }
      #pragma unroll
      for (int mi = 0; mi < 4; ++mi)
        #pragma unroll
        for (int ni = 0; ni < 4; ++ni)
          acc[mi][ni] = __builtin_amdgcn_mfma_f32_16x16x32_bf16(af[mi], bfr[ni], acc[mi][ni], 0, 0, 0);
    }
  }

  if (!vhalf) {
    #pragma unroll
    for (int mi = 0; mi < 4; ++mi)
      #pragma unroll
      for (int r = 0; r < 4; ++r) {
        int s = bm + wm * 64 + mi * 16 + lg * 4 + r;
        #pragma unroll
        for (int ni = 0; ni < 4; ++ni) {
          int c = wn * 64 + ni * 16 + lj;
          kv_nopeb[((size_t)s * NH_ + n) * 256 + c] = (__bf16)acc[mi][ni][r];
        }
      }
  } else {
    #pragma unroll
    for (int mi = 0; mi < 4; ++mi)
      #pragma unroll
      for (int r = 0; r < 4; ++r) {
        int h = wm * 64 + mi * 16 + lg * 4 + r;
        __bf16* dst = Vt + ((size_t)n * HV_ + h) * T_ + bm;
        #pragma unroll
        for (int ni = 0; ni < 4; ++ni) {
          int s = wn * 64 + ni * 16 + lj;
          dst[s] = (__bf16)acc[mi][ni][r];
        }
      }
  }
}

// ============ fp32 [K][N] -> bf16 [N][K] transpose (weights) ============
__global__ __launch_bounds__(256) void transpose_bf16_kernel(
    const float* __restrict__ B, __bf16* __restrict__ Bt, int K, int N) {
  __shared__ float tile[64][65];
  int n0 = blockIdx.x * 64, k0 = blockIdx.y * 64;
  int tid = threadIdx.x;
  int kr = tid >> 4, nc = (tid & 15) * 4;
  #pragma unroll
  for (int i = 0; i < 4; ++i) {
    int k = kr + i * 16;
    float4 v = make_float4(0.f, 0.f, 0.f, 0.f);
    if (n0 + nc < N) v = *(const float4*)(B + (size_t)(k0 + k) * N + n0 + nc);
    tile[k][nc + 0] = v.x; tile[k][nc + 1] = v.y;
    tile[k][nc + 2] = v.z; tile[k][nc + 3] = v.w;
  }
  __syncthreads();
  int nl = tid >> 4, k4 = (tid & 15) * 4;
  #pragma unroll
  for (int i = 0; i < 4; ++i) {
    int nn = nl + i * 16;
    bf16x4 o;
    o[0] = (__bf16)tile[k4 + 0][nn]; o[1] = (__bf16)tile[k4 + 1][nn];
    o[2] = (__bf16)tile[k4 + 2][nn]; o[3] = (__bf16)tile[k4 + 3][nn];
    *(bf16x4*)(Bt + (size_t)(n0 + nn) * K + k0 + k4) = o;
  }
}

// ============ RMSNorm (bf16 in, bf16 out) ============
__global__ __launch_bounds__(256) void rmsnorm_bf16_kernel(
    const __bf16* __restrict__ in, __bf16* __restrict__ out,
    const float* __restrict__ scale, int len, int in_stride) {
  int row = blockIdx.x;
  const __bf16* x = in + (size_t)row * in_stride;
  __bf16* y = out + (size_t)row * len;
  float ss = 0.f;
  for (int i = threadIdx.x; i < len; i += 256) { float v = (float)x[i]; ss += v * v; }
  __shared__ float red[4];
  #pragma unroll
  for (int o = 32; o > 0; o >>= 1) ss += __shfl_down(ss, o, 64);
  int wid = threadIdx.x >> 6, lane = threadIdx.x & 63;
  if (lane == 0) red[wid] = ss;
  __syncthreads();
  if (threadIdx.x == 0) {
    float t = red[0] + red[1] + red[2] + red[3];
    red[0] = 1.0f / sqrtf(t / (float)len + 1e-6f);
  }
  __syncthreads();
  float r = red[0];
  for (int i = threadIdx.x; i < len; i += 256) y[i] = (__bf16)((float)x[i] * r * scale[i]);
}

// ============ RoPE table ============
struct InvFreq { float f[32]; };
__global__ __launch_bounds__(256) void rope_table_kernel(
    const int* __restrict__ pos, float* __restrict__ cosT, float* __restrict__ sinT,
    InvFreq invf) {
  int idx = blockIdx.x * 256 + threadIdx.x;
  if (idx >= T_ * 32) return;
  int t = idx >> 5, i = idx & 31;
  float fr = (float)pos[t] * invf.f[i];
  cosT[idx] = cosf(fr);
  sinT[idx] = sinf(fr);
}

// ============ RoPE on k (bf16 strided src -> bf16 k_rope) ============
__global__ __launch_bounds__(256) void rope_k_kernel(
    const __bf16* __restrict__ src, int stride, const float* __restrict__ cosT,
    const float* __restrict__ sinT, __bf16* __restrict__ k_rope) {
  int idx = blockIdx.x * 256 + threadIdx.x;   // T*32
  if (idx >= T_ * 32) return;
  int t = idx >> 5, i = idx & 31;
  const __bf16* b = src + (size_t)t * stride;
  float x1 = (float)b[i], x2 = (float)b[i + 32];
  float c = cosT[idx], s = sinT[idx];
  k_rope[t * 64 + i]      = (__bf16)(x1 * c - x2 * s);
  k_rope[t * 64 + i + 32] = (__bf16)(x1 * s + x2 * c);
}

// ============ MFMA flash attention v9: shared-KV dual q-tile blocks ============
__global__ __launch_bounds__(256, 2) void attn_mfma_kernel(
    const __bf16* __restrict__ q_tnh, const __bf16* __restrict__ kv_nopeb,
    const __bf16* __restrict__ k_rope, const __bf16* __restrict__ Vt,
    __bf16* __restrict__ attn_out, float sm_scale2) {  // includes *log2(e)
  __shared__ __bf16 KsL[2][24 * 64 * 8];   // [c][s][8], 24 KB per buf
  __shared__ __bf16 Vs[8 * 128 * 8];       // [c][h][8], 16 KB (single buffer)
  __shared__ __bf16 Ps[4][32 * 64];        // per-wave P, rows f*16+rw, 16 KB
  const int tid = threadIdx.x;
  const int lane = tid & 63;
  const int w = tid >> 6;
  const int id = blockIdx.x;               // 512 blocks
  const int j = id >> 3;
  const int p = j >> 2;                    // pair index 0..15
  const int n = (id & 7) * 4 + (j & 3);    // XCD head-affinity
  const int lg = lane >> 4;
  const int lj = lane & 15;
  const int qtf0 = p, qtf1 = 31 - p;

  const __bf16* kptr[6]; size_t kstep[6]; int klds[6];
  #pragma unroll
  for (int i = 0; i < 6; ++i) {
    int task = i * 256 + tid;
    int c = task >> 6, s = task & 63;
    if (c < 16) { kptr[i] = kv_nopeb + ((size_t)s * NH_ + n) * 256 + c * 8; kstep[i] = (size_t)64 * NH_ * 256; }
    else        { kptr[i] = k_rope + (size_t)s * ROPE_ + (c - 16) * 8;      kstep[i] = (size_t)64 * ROPE_; }
    klds[i] = (i * 256 + w * 64) * 8;
  }
  const __bf16* vptr[4]; int vlds[4];
  #pragma unroll
  for (int i = 0; i < 4; ++i) {
    int task = i * 256 + tid;
    int c = task >> 7, h = task & 127;
    vptr[i] = Vt + ((size_t)n * HV_ + h) * T_ + c * 8;
    vlds[i] = (i * 256 + w * 64) * 8;
  }

  #define STAGE_K(bufIdx)                                                      \
    do {                                                                       \
      __bf16* kb_ = &KsL[bufIdx][0];                                           \
      _Pragma("unroll")                                                        \
      for (int i_ = 0; i_ < 6; ++i_) {                                         \
        gload_lds16(kptr[i_], kb_ + klds[i_]);                                 \
        kptr[i_] += kstep[i_];                                                 \
      }                                                                        \
    } while (0)
  #define STAGE_V()                                                            \
    do {                                                                       \
      _Pragma("unroll")                                                        \
      for (int i_ = 0; i_ < 4; ++i_) {                                         \
        gload_lds16(vptr[i_], &Vs[0] + vlds[i_]);                              \
        vptr[i_] += 64;                                                        \
      }                                                                        \
    } while (0)

  STAGE_K(0);

  bf16x8 qf[2][6];
  #pragma unroll
  for (int f = 0; f < 2; ++f) {
    int t = (f ? qtf1 : qtf0) * 64 + w * 16 + lj;
    const __bf16* qp = q_tnh + ((size_t)t * NH_ + n) * HQK_;
    #pragma unroll
    for (int kk = 0; kk < 6; ++kk) {
      bf16x8 raw = *(const bf16x8*)(qp + kk * 32 + lg * 8);
      bf16x8 v;
      #pragma unroll
      for (int i = 0; i < 8; ++i) v[i] = (__bf16)((float)raw[i] * sm_scale2);
      qf[f][kk] = v;
    }
  }

  f32x4 O[2][8];
  float m_r[2][4], l_r[2][4];
  #pragma unroll
  for (int f = 0; f < 2; ++f) {
    #pragma unroll
    for (int nb = 0; nb < 8; ++nb) O[f][nb] = (f32x4){0.f, 0.f, 0.f, 0.f};
    #pragma unroll
    for (int r = 0; r < 4; ++r) { m_r[f][r] = -1e30f; l_r[f][r] = 0.f; }
  }

  __syncthreads();

  const int nst = 32 - p;
  #pragma unroll 1
  for (int st = 0; st < nst; ++st) {
    const int s0 = st * 64;
    const int cur = st & 1;
    if (st + 1 < nst) STAGE_K(cur ^ 1);
    STAGE_V();
    const __bf16* kb = &KsL[cur][0];
    const bool act0 = (st <= qtf0);

    #pragma unroll
    for (int f = 0; f < 2; ++f) {
      if (f == 0 && !act0) continue;
      const int qt = f ? qtf1 : qtf0;
      const int rowbase = qt * 64 + w * 16;
      f32x4 S[4];
      __builtin_amdgcn_s_setprio(1);
      #pragma unroll
      for (int sb = 0; sb < 4; ++sb) {
        f32x4 acc = (f32x4){0.f, 0.f, 0.f, 0.f};
        int srow = sb * 16 + lj;
        #pragma unroll
        for (int kk = 0; kk < 6; ++kk) {
          int c = kk * 4 + lg;
          bf16x8 b = *(const bf16x8*)&kb[(c * 64 + srow) * 8];
          acc = __builtin_amdgcn_mfma_f32_16x16x32_bf16(qf[f][kk], b, acc, 0, 0, 0);
        }
        S[sb] = acc;
      }
      __builtin_amdgcn_s_setprio(0);
      if (st == qt) {
        #pragma unroll
        for (int sb = 0; sb < 4; ++sb)
          #pragma unroll
          for (int r = 0; r < 4; ++r) {
            int row = rowbase + lg * 4 + r;
            int col = s0 + sb * 16 + lj;
            if (col > row) S[sb][r] = -1e30f;
          }
      }
      float mx[4];
      #pragma unroll
      for (int r = 0; r < 4; ++r) {
        float m2 = fmaxf(fmaxf(S[0][r], S[1][r]), fmaxf(S[2][r], S[3][r]));
        m2 = fmaxf(m2, __shfl_xor(m2, 1));
        m2 = fmaxf(m2, __shfl_xor(m2, 2));
        m2 = fmaxf(m2, __shfl_xor(m2, 4));
        m2 = fmaxf(m2, __shfl_xor(m2, 8));
        mx[r] = m2;
      }
      int need = (mx[0] > m_r[f][0]) | (mx[1] > m_r[f][1]) |
                 (mx[2] > m_r[f][2]) | (mx[3] > m_r[f][3]);
      if (__any(need)) {
        #pragma unroll
        for (int r = 0; r < 4; ++r) {
          float mnew = fmaxf(m_r[f][r], mx[r]);
          float corr = __builtin_amdgcn_exp2f(m_r[f][r] - mnew);
          m_r[f][r] = mnew;
          l_r[f][r] *= corr;
          #pragma unroll
          for (int nb = 0; nb < 8; ++nb) O[f][nb][r] = O[f][nb][r] * corr;
        }
      }
      #pragma unroll
      for (int r = 0; r < 4; ++r) {
        float psum = 0.f;
        #pragma unroll
        for (int sb = 0; sb < 4; ++sb) {
          float pp = __builtin_amdgcn_exp2f(S[sb][r] - m_r[f][r]);
          S[sb][r] = pp;
          psum += pp;
        }
        l_r[f][r] += psum;
      }
      #pragma unroll
      for (int sb = 0; sb < 4; ++sb) {
        int sl = sb * 16 + lj;
        int c = sl >> 3;
        #pragma unroll
        for (int r = 0; r < 4; ++r) {
          int rw = lg * 4 + r;
          Ps[w][(f * 16 + rw) * 64 + ((c ^ (rw & 7)) << 3) + (sl & 7)] = (__bf16)S[sb][r];
        }
      }
    }
    __syncthreads();
    __builtin_amdgcn_s_setprio(1);
    #pragma unroll
    for (int f = 0; f < 2; ++f) {
      if (f == 0 && !act0) continue;
      #pragma unroll
      for (int kk = 0; kk < 2; ++kk) {
        int ca = kk * 4 + lg;
        bf16x8 pa = *(const bf16x8*)&Ps[w][(f * 16 + lj) * 64 + ((ca ^ (lj & 7)) << 3)];
        #pragma unroll
        for (int nb = 0; nb < 8; ++nb) {
          int h = nb * 16 + lj;
          bf16x8 bv = *(const bf16x8*)&Vs[(ca * 128 + h) * 8];
          O[f][nb] = __builtin_amdgcn_mfma_f32_16x16x32_bf16(pa, bv, O[f][nb], 0, 0, 0);
        }
      }
    }
    __builtin_amdgcn_s_setprio(0);
    __syncthreads();
  }

  #pragma unroll
  for (int f = 0; f < 2; ++f) {
    const int qt = f ? qtf1 : qtf0;
    #pragma unroll
    for (int r = 0; r < 4; ++r) {
      float lsum = l_r[f][r];
      lsum += __shfl_xor(lsum, 1);
      lsum += __shfl_xor(lsum, 2);
      lsum += __shfl_xor(lsum, 4);
      lsum += __shfl_xor(lsum, 8);
      float inv = 1.0f / lsum;
      int t = qt * 64 + w * 16 + lg * 4 + r;
      __bf16* dst = attn_out + ((size_t)t * NH_ + n) * HV_;
      #pragma unroll
      for (int nb = 0; nb < 8; ++nb) dst[nb * 16 + lj] = (__bf16)(O[f][nb][r] * inv);
    }
  }
  #undef STAGE_K
  #undef STAGE_V
}

// ================= host side =================
static void compute_inv_freq(float* out) {
  const double theta = 10000.0, factor = 40.0;
  const double PI = 3.14159265358979323846;
  const int rot = ROPE_;
  double low_d  = rot * log(4096.0 / (32.0 * 2.0 * PI)) / (2.0 * log(theta));
  double high_d = rot * log(4096.0 / ( 1.0 * 2.0 * PI)) / (2.0 * log(theta));
  double low = floor(low_d);  if (low < 0) low = 0;
  double high = ceil(high_d); if (high > rot - 1) high = rot - 1;
  for (int i = 0; i < 32; ++i) {
    double pf = pow(theta, (2.0 * i) / (double)rot);
    double inv_extra = 1.0 / pf;
    double inv_inter = 1.0 / (factor * pf);
    double ramp = ((double)i - low) / fmax(high - low, 0.001);
    ramp = fmin(fmax(ramp, 0.0), 1.0);
    double mask = 1.0 - ramp;
    out[i] = (float)(inv_inter * (1.0 - mask) + inv_extra * mask);
  }
}

extern "C" void kernel_launch(void* const* d_in, const int* in_sizes, int n_in,
                              void* d_out, int out_size, void* d_ws, size_t ws_size,
                              hipStream_t stream) {
  const float* x            = (const float*)d_in[0];
  const int*   positions    = (const int*)d_in[1];
  const float* w_q_down     = (const float*)d_in[2];
  const float* q_norm_scale = (const float*)d_in[3];
  const float* w_q_up       = (const float*)d_in[4];
  const float* w_kv_down    = (const float*)d_in[5];
  const float* kv_norm_scale= (const float*)d_in[6];
  const float* w_kv_up      = (const float*)d_in[7];
  const float* w_o          = (const float*)d_in[8];
  float* out = (float*)d_out;

  // ---- workspace (float offsets); layout as R14 (xb region now unused) ----
  float* ws = (float*)d_ws;
  float*  cosT     = ws;                           // live through q_up (fused rope)
  float*  sinT     = ws + 65536;
  __bf16* catb     = (__bf16*)(ws + 131072);       // T*2112 bf16; dead@rope_k
  __bf16* Bt_cat   = (__bf16*)(ws + 8650752);      // dead@down-gemm
  __bf16* Bt_qu    = (__bf16*)(ws + 13107200);     // dead@qup-gemm
  __bf16* Bt_kvu   = (__bf16*)(ws + 17825792);     // dead@kvup-gemm
  __bf16* q_tab    = (__bf16*)(ws + 19922944);     // dead@qup-gemm
  __bf16* kv_latb  = (__bf16*)(ws + 21495808);     // dead@kvup-gemm
  __bf16* k_ropeb  = (__bf16*)(ws + 22020096);     // dead@attn
  __bf16* q_tnhb   = (__bf16*)(ws + 22085632);     // dead@attn
  __bf16* kv_nopeb = (__bf16*)(ws + 28377088);     // dead@attn
  // aliases (target regions dead before first write):
  __bf16* Vt       = (__bf16*)(ws + 13107200);     // over Bt_qu (dead after q_up)
  __bf16* attn_ob  = (__bf16*)(ws + 17825792);     // over Bt_kvu+q_tab+kv_latb
  __bf16* Bt_o     = (__bf16*)(ws + 4456448);      // over old-xb+Bt_cat
  (void)ws_size; (void)n_in; (void)in_sizes; (void)out_size;

  InvFreq invf;
  compute_inv_freq(invf.f);
  double ym = 0.1 * log(40.0) + 1.0;
  float sm_scale2 = (float)((ym * ym / sqrt((double)HQK_)) * 1.44269504088896340736);

  // tables + weight transposes (x conv eliminated: down-proj reads fp32 x)
  rope_table_kernel<<<(T_ * 32 + 255) / 256, 256, 0, stream>>>(positions, cosT, sinT, invf);
  transpose_bf16_kernel<<<dim3(QL_ / 64, D_ / 64), 256, 0, stream>>>(w_q_down, Bt_cat, D_, QL_);
  transpose_bf16_kernel<<<dim3(KVD_ / 64, D_ / 64), 256, 0, stream>>>(w_kv_down, Bt_cat + (size_t)QL_ * D_, D_, KVD_);
  transpose_bf16_kernel<<<dim3(NH_ * HQK_ / 64, QL_ / 64), 256, 0, stream>>>(w_q_up, Bt_qu, QL_, NH_ * HQK_);
  transpose_bf16_kernel<<<dim3(NH_ * 256 / 64, KVL_ / 64), 256, 0, stream>>>(w_kv_up, Bt_kvu, KVL_, NH_ * 256);

  // fused down-projection (fp32 A, BK=128): catb = x @ [w_q_down | w_kv_down]
  downproj_gemm_kernel<<<dim3((NCAT_ + 127) / 128, T_ / 128), 256, 0, stream>>>(x, Bt_cat, catb, T_, NCAT_, D_);

  // q path (rope fused into q_up epilogue)
  rmsnorm_bf16_kernel<<<T_, 256, 0, stream>>>(catb, q_tab, q_norm_scale, QL_, NCAT_);
  qup_gemm_kernel<<<dim3(NH_ * HQK_ / 128, T_ / 128), 256, 0, stream>>>(q_tab, Bt_qu, q_tnhb, cosT, sinT, T_, NH_ * HQK_, QL_);

  // kv path: fused kv_up (nope -> kv_nopeb, V -> Vt transposed)
  rmsnorm_bf16_kernel<<<T_, 256, 0, stream>>>(catb + QL_, kv_latb, kv_norm_scale, KVL_, NCAT_);
  rope_k_kernel<<<(T_ * 32 + 255) / 256, 256, 0, stream>>>(catb + QL_ + KVL_, NCAT_, cosT, sinT, k_ropeb);
  kvup_gemm_kernel<<<dim3(NH_ * 2, T_ / 128), 256, 0, stream>>>(kv_latb, Bt_kvu, kv_nopeb, Vt);

  // attention (512 dual-q blocks, shared KV staging, XCD head-affinity)
  attn_mfma_kernel<<<512, 256, 0, stream>>>(q_tnhb, kv_nopeb, k_ropeb, Vt, attn_ob, sm_scale2);

  // output projection
  transpose_bf16_kernel<<<dim3(D_ / 64, NH_ * HV_ / 64), 256, 0, stream>>>(w_o, Bt_o, NH_ * HV_, D_);
  mfma_gemm_kernel<float><<<dim3(D_ / 128, T_ / 128), 256, 0, stream>>>(attn_ob, Bt_o, out, T_, D_, NH_ * HV_);
}

// Round 16
// 387.732 us; speedup vs baseline: 1.0551x; 1.0551x over previous
//
#include <hip/hip_runtime.h>
#include <math.h>
#include <stdint.h>

// ---- problem constants ----
#define T_    2048
#define D_    4096
#define NH_   32
#define QL_   1536     // Q_LORA
#define KVL_  512      // KV_LORA
#define ROPE_ 64       // QK_ROPE
#define NOPE_ 128      // QK_NOPE
#define HQK_  192      // QK_HEAD
#define HV_   128      // V_HEAD
#define KVD_  576      // KV_LORA + QK_ROPE
#define NCAT_ 2112     // QL_ + KVD_ (fused down-projection width)

typedef __bf16 bf16x8 __attribute__((ext_vector_type(8)));
typedef __bf16 bf16x4 __attribute__((ext_vector_type(4)));
typedef float f32x4 __attribute__((ext_vector_type(4)));

// async global->LDS, 16B per lane. LDS dest = wave-uniform base + lane*16.
__device__ __forceinline__ void gload_lds16(const __bf16* g, __bf16* l) {
  __builtin_amdgcn_global_load_lds(
      (const __attribute__((address_space(1))) void*)g,
      (__attribute__((address_space(3))) void*)l, 16, 0, 0);
}

// ============ bf16 MFMA GEMM (m97 structure): C[M][N] = A[M][K] * Bt[N][K]^T ====
// 128x128 tile, BK=64, 256 thr = 4 waves (2x2), each wave 64x64 = 4x4 frags.
template <typename OutT>
__global__ __launch_bounds__(256, 3) void mfma_gemm_kernel(
    const __bf16* __restrict__ A, const __bf16* __restrict__ Bt,
    OutT* __restrict__ C, int M, int Ncols, int K) {
  __shared__ __bf16 As[128 * 64];   // 16 KB
  __shared__ __bf16 Bs[128 * 64];   // 16 KB
  const int tid = threadIdx.x;
  const int lane = tid & 63;
  const int w = tid >> 6;
  const int wm = w >> 1, wn = w & 1;
  const int lg = lane >> 4, lj = lane & 15;
  const int bm = blockIdx.y * 128;
  const int bn = blockIdx.x * 128;

  const __bf16* ga[4]; const __bf16* gb[4];
  int ldsoff[4];
  #pragma unroll
  for (int i = 0; i < 4; ++i) {
    int task = i * 256 + tid;
    int r = task >> 3, cl = task & 7;
    int cg = cl ^ (r & 7);
    ga[i] = A  + (size_t)(bm + r) * K + cg * 8;
    gb[i] = Bt + (size_t)(bn + r) * K + cg * 8;
    ldsoff[i] = (i * 256 + w * 64) * 8;
  }

  f32x4 acc[4][4];
  #pragma unroll
  for (int mi = 0; mi < 4; ++mi)
    #pragma unroll
    for (int ni = 0; ni < 4; ++ni) acc[mi][ni] = (f32x4){0.f, 0.f, 0.f, 0.f};

  for (int k0 = 0; k0 < K; k0 += 64) {
    __syncthreads();
    #pragma unroll
    for (int i = 0; i < 4; ++i) gload_lds16(ga[i] + k0, &As[ldsoff[i]]);
    #pragma unroll
    for (int i = 0; i < 4; ++i) gload_lds16(gb[i] + k0, &Bs[ldsoff[i]]);
    __syncthreads();
    #pragma unroll
    for (int kh = 0; kh < 2; ++kh) {
      bf16x8 af[4], bfr[4];
      #pragma unroll
      for (int i = 0; i < 4; ++i) {
        int ra = wm * 64 + i * 16 + lj;
        af[i] = *(const bf16x8*)&As[ra * 64 + ((((kh << 2) + lg) ^ (ra & 7)) << 3)];
      }
      #pragma unroll
      for (int i = 0; i < 4; ++i) {
        int rb = wn * 64 + i * 16 + lj;
        bfr[i] = *(const bf16x8*)&Bs[rb * 64 + ((((kh << 2) + lg) ^ (rb & 7)) << 3)];
      }
      #pragma unroll
      for (int mi = 0; mi < 4; ++mi)
        #pragma unroll
        for (int ni = 0; ni < 4; ++ni)
          acc[mi][ni] = __builtin_amdgcn_mfma_f32_16x16x32_bf16(af[mi], bfr[ni], acc[mi][ni], 0, 0, 0);
    }
  }

  #pragma unroll
  for (int mi = 0; mi < 4; ++mi) {
    #pragma unroll
    for (int r = 0; r < 4; ++r) {
      int row = bm + wm * 64 + mi * 16 + lg * 4 + r;
      #pragma unroll
      for (int ni = 0; ni < 4; ++ni) {
        int col = bn + wn * 64 + ni * 16 + lj;
        if (col < Ncols) C[(size_t)row * Ncols + col] = (OutT)acc[mi][ni][r];
      }
    }
  }
}

// ============ q_up GEMM with FUSED ROPE epilogue ============
// N = NH*HQK = 6144. A 64-wide wave-tile is a head's rope block iff
// (col0 % 192) == 128 (wave-uniform). Rope pair (i, i+32) = acc[.][ni] vs
// acc[.][ni+2], rotated in fp32 before the bf16 store.
__global__ __launch_bounds__(256, 3) void qup_gemm_kernel(
    const __bf16* __restrict__ A, const __bf16* __restrict__ Bt,
    __bf16* __restrict__ C, const float* __restrict__ cosT,
    const float* __restrict__ sinT, int M, int Ncols, int K) {
  __shared__ __bf16 As[128 * 64];
  __shared__ __bf16 Bs[128 * 64];
  const int tid = threadIdx.x;
  const int lane = tid & 63;
  const int w = tid >> 6;
  const int wm = w >> 1, wn = w & 1;
  const int lg = lane >> 4, lj = lane & 15;
  const int bm = blockIdx.y * 128;
  const int bn = blockIdx.x * 128;

  const __bf16* ga[4]; const __bf16* gb[4];
  int ldsoff[4];
  #pragma unroll
  for (int i = 0; i < 4; ++i) {
    int task = i * 256 + tid;
    int r = task >> 3, cl = task & 7;
    int cg = cl ^ (r & 7);
    ga[i] = A  + (size_t)(bm + r) * K + cg * 8;
    gb[i] = Bt + (size_t)(bn + r) * K + cg * 8;
    ldsoff[i] = (i * 256 + w * 64) * 8;
  }

  f32x4 acc[4][4];
  #pragma unroll
  for (int mi = 0; mi < 4; ++mi)
    #pragma unroll
    for (int ni = 0; ni < 4; ++ni) acc[mi][ni] = (f32x4){0.f, 0.f, 0.f, 0.f};

  for (int k0 = 0; k0 < K; k0 += 64) {
    __syncthreads();
    #pragma unroll
    for (int i = 0; i < 4; ++i) gload_lds16(ga[i] + k0, &As[ldsoff[i]]);
    #pragma unroll
    for (int i = 0; i < 4; ++i) gload_lds16(gb[i] + k0, &Bs[ldsoff[i]]);
    __syncthreads();
    #pragma unroll
    for (int kh = 0; kh < 2; ++kh) {
      bf16x8 af[4], bfr[4];
      #pragma unroll
      for (int i = 0; i < 4; ++i) {
        int ra = wm * 64 + i * 16 + lj;
        af[i] = *(const bf16x8*)&As[ra * 64 + ((((kh << 2) + lg) ^ (ra & 7)) << 3)];
      }
      #pragma unroll
      for (int i = 0; i < 4; ++i) {
        int rb = wn * 64 + i * 16 + lj;
        bfr[i] = *(const bf16x8*)&Bs[rb * 64 + ((((kh << 2) + lg) ^ (rb & 7)) << 3)];
      }
      #pragma unroll
      for (int mi = 0; mi < 4; ++mi)
        #pragma unroll
        for (int ni = 0; ni < 4; ++ni)
          acc[mi][ni] = __builtin_amdgcn_mfma_f32_16x16x32_bf16(af[mi], bfr[ni], acc[mi][ni], 0, 0, 0);
    }
  }

  const bool isrope = (((bn + wn * 64) % HQK_) == NOPE_);   // wave-uniform
  #pragma unroll
  for (int mi = 0; mi < 4; ++mi) {
    #pragma unroll
    for (int r = 0; r < 4; ++r) {
      int row = bm + wm * 64 + mi * 16 + lg * 4 + r;
      if (isrope) {
        #pragma unroll
        for (int ni = 0; ni < 2; ++ni) {
          int i = ni * 16 + lj;                 // 0..31
          float c = cosT[row * 32 + i];
          float s = sinT[row * 32 + i];
          float x1 = acc[mi][ni][r], x2 = acc[mi][ni + 2][r];
          acc[mi][ni][r]     = x1 * c - x2 * s;
          acc[mi][ni + 2][r] = x1 * s + x2 * c;
        }
      }
      #pragma unroll
      for (int ni = 0; ni < 4; ++ni) {
        int col = bn + wn * 64 + ni * 16 + lj;
        C[(size_t)row * Ncols + col] = (__bf16)acc[mi][ni][r];
      }
    }
  }
}

// ============ BK=128 variant for the down-projection (272 blocks = ~1/CU: ======
// halving barrier count halves exposed drains; async DMA staging — the R15
// fp32-reg-staging variant REGRESSED ~19us, no overlap partner at 1 block/CU).
template <typename OutT>
__global__ __launch_bounds__(256, 2) void mfma_gemm_bk128_kernel(
    const __bf16* __restrict__ A, const __bf16* __restrict__ Bt,
    OutT* __restrict__ C, int M, int Ncols, int K) {
  __shared__ __bf16 As[128 * 128];   // 32 KB
  __shared__ __bf16 Bs[128 * 128];   // 32 KB
  const int tid = threadIdx.x;
  const int lane = tid & 63;
  const int w = tid >> 6;
  const int wm = w >> 1, wn = w & 1;
  const int lg = lane >> 4, lj = lane & 15;
  const int bm = blockIdx.y * 128;
  const int bn = blockIdx.x * 128;

  const __bf16* ga[8]; const __bf16* gb[8];
  int ldsoff[8];
  #pragma unroll
  for (int i = 0; i < 8; ++i) {
    int task = i * 256 + tid;
    int r = task >> 4, cl = task & 15;
    int cg = (cl & 8) | ((cl & 7) ^ (r & 7));
    ga[i] = A  + (size_t)(bm + r) * K + cg * 8;
    gb[i] = Bt + (size_t)(bn + r) * K + cg * 8;
    ldsoff[i] = (i * 256 + w * 64) * 8;
  }

  f32x4 acc[4][4];
  #pragma unroll
  for (int mi = 0; mi < 4; ++mi)
    #pragma unroll
    for (int ni = 0; ni < 4; ++ni) acc[mi][ni] = (f32x4){0.f, 0.f, 0.f, 0.f};

  for (int k0 = 0; k0 < K; k0 += 128) {
    __syncthreads();
    #pragma unroll
    for (int i = 0; i < 8; ++i) gload_lds16(ga[i] + k0, &As[ldsoff[i]]);
    #pragma unroll
    for (int i = 0; i < 8; ++i) gload_lds16(gb[i] + k0, &Bs[ldsoff[i]]);
    __syncthreads();
    #pragma unroll
    for (int kh = 0; kh < 4; ++kh) {
      bf16x8 af[4], bfr[4];
      #pragma unroll
      for (int i = 0; i < 4; ++i) {
        int ra = wm * 64 + i * 16 + lj;
        int kc = (kh << 2) + lg;
        int slot = (kc & 8) | ((kc & 7) ^ (ra & 7));
        af[i] = *(const bf16x8*)&As[ra * 128 + (slot << 3)];
      }
      #pragma unroll
      for (int i = 0; i < 4; ++i) {
        int rb = wn * 64 + i * 16 + lj;
        int kc = (kh << 2) + lg;
        int slot = (kc & 8) | ((kc & 7) ^ (rb & 7));
        bfr[i] = *(const bf16x8*)&Bs[rb * 128 + (slot << 3)];
      }
      #pragma unroll
      for (int mi = 0; mi < 4; ++mi)
        #pragma unroll
        for (int ni = 0; ni < 4; ++ni)
          acc[mi][ni] = __builtin_amdgcn_mfma_f32_16x16x32_bf16(af[mi], bfr[ni], acc[mi][ni], 0, 0, 0);
    }
  }

  #pragma unroll
  for (int mi = 0; mi < 4; ++mi) {
    #pragma unroll
    for (int r = 0; r < 4; ++r) {
      int row = bm + wm * 64 + mi * 16 + lg * 4 + r;
      #pragma unroll
      for (int ni = 0; ni < 4; ++ni) {
        int col = bn + wn * 64 + ni * 16 + lj;
        if (col < Ncols) C[(size_t)row * Ncols + col] = (OutT)acc[mi][ni][r];
      }
    }
  }
}

// ============ kv_up GEMM with fused V-transpose output ============
__global__ __launch_bounds__(256, 3) void kvup_gemm_kernel(
    const __bf16* __restrict__ A /*kv_latb [T][512]*/,
    const __bf16* __restrict__ Bt /*Bt_kvu [8192][512]*/,
    __bf16* __restrict__ kv_nopeb /*[T][NH][256]*/,
    __bf16* __restrict__ Vt /*[NH][HV][T]*/) {
  __shared__ __bf16 As[128 * 64];
  __shared__ __bf16 Bs[128 * 64];
  const int tid = threadIdx.x;
  const int lane = tid & 63;
  const int w = tid >> 6;
  const int wm = w >> 1, wn = w & 1;
  const int lg = lane >> 4, lj = lane & 15;
  const int bm = blockIdx.y * 128;          // token rows
  const int bn = blockIdx.x * 128;          // Bt rows (flattened n*256 + j)
  const int n = blockIdx.x >> 1;
  const bool vhalf = (blockIdx.x & 1) != 0;
  const int K = KVL_;

  const __bf16* ga[4]; const __bf16* gb[4];
  int ldsoff[4];
  #pragma unroll
  for (int i = 0; i < 4; ++i) {
    int task = i * 256 + tid;
    int r = task >> 3, cl = task & 7;
    int cg = cl ^ (r & 7);
    ga[i] = A  + (size_t)(bm + r) * K + cg * 8;
    gb[i] = Bt + (size_t)(bn + r) * K + cg * 8;
    ldsoff[i] = (i * 256 + w * 64) * 8;
  }

  const __bf16* RowT = vhalf ? &Bs[0] : &As[0];
  const __bf16* ColT = vhalf ? &As[0] : &Bs[0];

  f32x4 acc[4][4];
  #pragma unroll
  for (int mi = 0; mi < 4; ++mi)
    #pragma unroll
    for (int ni = 0; ni < 4; ++ni) acc[mi][ni] = (f32x4){0.f, 0.f, 0.f, 0.f};

  for (int k0 = 0; k0 < K; k0 += 64) {
    __syncthreads();
    #pragma unroll
    for (int i = 0; i < 4; ++i) gload_lds16(ga[i] + k0, &As[ldsoff[i]]);
    #pragma unroll
    for (int i = 0; i < 4; ++i) gload_lds16(gb[i] + k0, &Bs[ldsoff[i]]);
    __syncthreads();
    #pragma unroll
    for (int kh = 0; kh < 2; ++kh) {
      bf16x8 af[4], bfr[4];
      #pragma unroll
      for (int i = 0; i < 4; ++i) {
        int ra = wm * 64 + i * 16 + lj;
        af[i] = *(const bf16x8*)&RowT[ra * 64 + ((((kh << 2) + lg) ^ (ra & 7)) << 3)];
      }
      #pragma unroll
      for (int i = 0; i < 4; ++i) {
        int rb = wn * 64 + i * 16 + lj;
        bfr[i] = *(const bf16x8*)&ColT[rb * 64 + ((((kh << 2) + lg) ^ (rb & 7)) << 3)];
      }
      #pragma unroll
      for (int mi = 0; mi < 4; ++mi)
        #pragma unroll
        for (int ni = 0; ni < 4; ++ni)
          acc[mi][ni] = __builtin_amdgcn_mfma_f32_16x16x32_bf16(af[mi], bfr[ni], acc[mi][ni], 0, 0, 0);
    }
  }

  if (!vhalf) {
    #pragma unroll
    for (int mi = 0; mi < 4; ++mi)
      #pragma unroll
      for (int r = 0; r < 4; ++r) {
        int s = bm + wm * 64 + mi * 16 + lg * 4 + r;
        #pragma unroll
        for (int ni = 0; ni < 4; ++ni) {
          int c = wn * 64 + ni * 16 + lj;
          kv_nopeb[((size_t)s * NH_ + n) * 256 + c] = (__bf16)acc[mi][ni][r];
        }
      }
  } else {
    #pragma unroll
    for (int mi = 0; mi < 4; ++mi)
      #pragma unroll
      for (int r = 0; r < 4; ++r) {
        int h = wm * 64 + mi * 16 + lg * 4 + r;
        __bf16* dst = Vt + ((size_t)n * HV_ + h) * T_ + bm;
        #pragma unroll
        for (int ni = 0; ni < 4; ++ni) {
          int s = wn * 64 + ni * 16 + lj;
          dst[s] = (__bf16)acc[mi][ni][r];
        }
      }
  }
}

// ============ fp32 [K][N] -> bf16 [N][K] transpose (weights) ============
__global__ __launch_bounds__(256) void transpose_bf16_kernel(
    const float* __restrict__ B, __bf16* __restrict__ Bt, int K, int N) {
  __shared__ float tile[64][65];
  int n0 = blockIdx.x * 64, k0 = blockIdx.y * 64;
  int tid = threadIdx.x;
  int kr = tid >> 4, nc = (tid & 15) * 4;
  #pragma unroll
  for (int i = 0; i < 4; ++i) {
    int k = kr + i * 16;
    float4 v = make_float4(0.f, 0.f, 0.f, 0.f);
    if (n0 + nc < N) v = *(const float4*)(B + (size_t)(k0 + k) * N + n0 + nc);
    tile[k][nc + 0] = v.x; tile[k][nc + 1] = v.y;
    tile[k][nc + 2] = v.z; tile[k][nc + 3] = v.w;
  }
  __syncthreads();
  int nl = tid >> 4, k4 = (tid & 15) * 4;
  #pragma unroll
  for (int i = 0; i < 4; ++i) {
    int nn = nl + i * 16;
    bf16x4 o;
    o[0] = (__bf16)tile[k4 + 0][nn]; o[1] = (__bf16)tile[k4 + 1][nn];
    o[2] = (__bf16)tile[k4 + 2][nn]; o[3] = (__bf16)tile[k4 + 3][nn];
    *(bf16x4*)(Bt + (size_t)(n0 + nn) * K + k0 + k4) = o;
  }
}

// ============ fp32 -> bf16 elementwise ============
__global__ __launch_bounds__(256) void conv_bf16_kernel(
    const float* __restrict__ in, __bf16* __restrict__ out, int n8) {
  int i = blockIdx.x * 256 + threadIdx.x;
  if (i >= n8) return;
  float4 a = *(const float4*)(in + (size_t)i * 8);
  float4 b = *(const float4*)(in + (size_t)i * 8 + 4);
  bf16x8 v;
  v[0] = (__bf16)a.x; v[1] = (__bf16)a.y; v[2] = (__bf16)a.z; v[3] = (__bf16)a.w;
  v[4] = (__bf16)b.x; v[5] = (__bf16)b.y; v[6] = (__bf16)b.z; v[7] = (__bf16)b.w;
  *(bf16x8*)(out + (size_t)i * 8) = v;
}

// ============ RMSNorm (bf16 in, bf16 out) ============
__global__ __launch_bounds__(256) void rmsnorm_bf16_kernel(
    const __bf16* __restrict__ in, __bf16* __restrict__ out,
    const float* __restrict__ scale, int len, int in_stride) {
  int row = blockIdx.x;
  const __bf16* x = in + (size_t)row * in_stride;
  __bf16* y = out + (size_t)row * len;
  float ss = 0.f;
  for (int i = threadIdx.x; i < len; i += 256) { float v = (float)x[i]; ss += v * v; }
  __shared__ float red[4];
  #pragma unroll
  for (int o = 32; o > 0; o >>= 1) ss += __shfl_down(ss, o, 64);
  int wid = threadIdx.x >> 6, lane = threadIdx.x & 63;
  if (lane == 0) red[wid] = ss;
  __syncthreads();
  if (threadIdx.x == 0) {
    float t = red[0] + red[1] + red[2] + red[3];
    red[0] = 1.0f / sqrtf(t / (float)len + 1e-6f);
  }
  __syncthreads();
  float r = red[0];
  for (int i = threadIdx.x; i < len; i += 256) y[i] = (__bf16)((float)x[i] * r * scale[i]);
}

// ============ RoPE table ============
struct InvFreq { float f[32]; };
__global__ __launch_bounds__(256) void rope_table_kernel(
    const int* __restrict__ pos, float* __restrict__ cosT, float* __restrict__ sinT,
    InvFreq invf) {
  int idx = blockIdx.x * 256 + threadIdx.x;
  if (idx >= T_ * 32) return;
  int t = idx >> 5, i = idx & 31;
  float fr = (float)pos[t] * invf.f[i];
  cosT[idx] = cosf(fr);
  sinT[idx] = sinf(fr);
}

// ============ RoPE on k (bf16 strided src -> bf16 k_rope) ============
__global__ __launch_bounds__(256) void rope_k_kernel(
    const __bf16* __restrict__ src, int stride, const float* __restrict__ cosT,
    const float* __restrict__ sinT, __bf16* __restrict__ k_rope) {
  int idx = blockIdx.x * 256 + threadIdx.x;   // T*32
  if (idx >= T_ * 32) return;
  int t = idx >> 5, i = idx & 31;
  const __bf16* b = src + (size_t)t * stride;
  float x1 = (float)b[i], x2 = (float)b[i + 32];
  float c = cosT[idx], s = sinT[idx];
  k_rope[t * 64 + i]      = (__bf16)(x1 * c - x2 * s);
  k_rope[t * 64 + i + 32] = (__bf16)(x1 * s + x2 * c);
}

// ============ MFMA flash attention v9: shared-KV dual q-tile blocks ============
__global__ __launch_bounds__(256, 2) void attn_mfma_kernel(
    const __bf16* __restrict__ q_tnh, const __bf16* __restrict__ kv_nopeb,
    const __bf16* __restrict__ k_rope, const __bf16* __restrict__ Vt,
    __bf16* __restrict__ attn_out, float sm_scale2) {  // includes *log2(e)
  __shared__ __bf16 KsL[2][24 * 64 * 8];   // [c][s][8], 24 KB per buf
  __shared__ __bf16 Vs[8 * 128 * 8];       // [c][h][8], 16 KB (single buffer)
  __shared__ __bf16 Ps[4][32 * 64];        // per-wave P, rows f*16+rw, 16 KB
  const int tid = threadIdx.x;
  const int lane = tid & 63;
  const int w = tid >> 6;
  const int id = blockIdx.x;               // 512 blocks
  const int j = id >> 3;
  const int p = j >> 2;                    // pair index 0..15
  const int n = (id & 7) * 4 + (j & 3);    // XCD head-affinity
  const int lg = lane >> 4;
  const int lj = lane & 15;
  const int qtf0 = p, qtf1 = 31 - p;

  const __bf16* kptr[6]; size_t kstep[6]; int klds[6];
  #pragma unroll
  for (int i = 0; i < 6; ++i) {
    int task = i * 256 + tid;
    int c = task >> 6, s = task & 63;
    if (c < 16) { kptr[i] = kv_nopeb + ((size_t)s * NH_ + n) * 256 + c * 8; kstep[i] = (size_t)64 * NH_ * 256; }
    else        { kptr[i] = k_rope + (size_t)s * ROPE_ + (c - 16) * 8;      kstep[i] = (size_t)64 * ROPE_; }
    klds[i] = (i * 256 + w * 64) * 8;
  }
  const __bf16* vptr[4]; int vlds[4];
  #pragma unroll
  for (int i = 0; i < 4; ++i) {
    int task = i * 256 + tid;
    int c = task >> 7, h = task & 127;
    vptr[i] = Vt + ((size_t)n * HV_ + h) * T_ + c * 8;
    vlds[i] = (i * 256 + w * 64) * 8;
  }

  #define STAGE_K(bufIdx)                                                      \
    do {                                                                       \
      __bf16* kb_ = &KsL[bufIdx][0];                                           \
      _Pragma("unroll")                                                        \
      for (int i_ = 0; i_ < 6; ++i_) {                                         \
        gload_lds16(kptr[i_], kb_ + klds[i_]);                                 \
        kptr[i_] += kstep[i_];                                                 \
      }                                                                        \
    } while (0)
  #define STAGE_V()                                                            \
    do {                                                                       \
      _Pragma("unroll")                                                        \
      for (int i_ = 0; i_ < 4; ++i_) {                                         \
        gload_lds16(vptr[i_], &Vs[0] + vlds[i_]);                              \
        vptr[i_] += 64;                                                        \
      }                                                                        \
    } while (0)

  STAGE_K(0);

  bf16x8 qf[2][6];
  #pragma unroll
  for (int f = 0; f < 2; ++f) {
    int t = (f ? qtf1 : qtf0) * 64 + w * 16 + lj;
    const __bf16* qp = q_tnh + ((size_t)t * NH_ + n) * HQK_;
    #pragma unroll
    for (int kk = 0; kk < 6; ++kk) {
      bf16x8 raw = *(const bf16x8*)(qp + kk * 32 + lg * 8);
      bf16x8 v;
      #pragma unroll
      for (int i = 0; i < 8; ++i) v[i] = (__bf16)((float)raw[i] * sm_scale2);
      qf[f][kk] = v;
    }
  }

  f32x4 O[2][8];
  float m_r[2][4], l_r[2][4];
  #pragma unroll
  for (int f = 0; f < 2; ++f) {
    #pragma unroll
    for (int nb = 0; nb < 8; ++nb) O[f][nb] = (f32x4){0.f, 0.f, 0.f, 0.f};
    #pragma unroll
    for (int r = 0; r < 4; ++r) { m_r[f][r] = -1e30f; l_r[f][r] = 0.f; }
  }

  __syncthreads();

  const int nst = 32 - p;
  #pragma unroll 1
  for (int st = 0; st < nst; ++st) {
    const int s0 = st * 64;
    const int cur = st & 1;
    if (st + 1 < nst) STAGE_K(cur ^ 1);
    STAGE_V();
    const __bf16* kb = &KsL[cur][0];
    const bool act0 = (st <= qtf0);

    #pragma unroll
    for (int f = 0; f < 2; ++f) {
      if (f == 0 && !act0) continue;
      const int qt = f ? qtf1 : qtf0;
      const int rowbase = qt * 64 + w * 16;
      f32x4 S[4];
      __builtin_amdgcn_s_setprio(1);
      #pragma unroll
      for (int sb = 0; sb < 4; ++sb) {
        f32x4 acc = (f32x4){0.f, 0.f, 0.f, 0.f};
        int srow = sb * 16 + lj;
        #pragma unroll
        for (int kk = 0; kk < 6; ++kk) {
          int c = kk * 4 + lg;
          bf16x8 b = *(const bf16x8*)&kb[(c * 64 + srow) * 8];
          acc = __builtin_amdgcn_mfma_f32_16x16x32_bf16(qf[f][kk], b, acc, 0, 0, 0);
        }
        S[sb] = acc;
      }
      __builtin_amdgcn_s_setprio(0);
      if (st == qt) {
        #pragma unroll
        for (int sb = 0; sb < 4; ++sb)
          #pragma unroll
          for (int r = 0; r < 4; ++r) {
            int row = rowbase + lg * 4 + r;
            int col = s0 + sb * 16 + lj;
            if (col > row) S[sb][r] = -1e30f;
          }
      }
      float mx[4];
      #pragma unroll
      for (int r = 0; r < 4; ++r) {
        float m2 = fmaxf(fmaxf(S[0][r], S[1][r]), fmaxf(S[2][r], S[3][r]));
        m2 = fmaxf(m2, __shfl_xor(m2, 1));
        m2 = fmaxf(m2, __shfl_xor(m2, 2));
        m2 = fmaxf(m2, __shfl_xor(m2, 4));
        m2 = fmaxf(m2, __shfl_xor(m2, 8));
        mx[r] = m2;
      }
      int need = (mx[0] > m_r[f][0]) | (mx[1] > m_r[f][1]) |
                 (mx[2] > m_r[f][2]) | (mx[3] > m_r[f][3]);
      if (__any(need)) {
        #pragma unroll
        for (int r = 0; r < 4; ++r) {
          float mnew = fmaxf(m_r[f][r], mx[r]);
          float corr = __builtin_amdgcn_exp2f(m_r[f][r] - mnew);
          m_r[f][r] = mnew;
          l_r[f][r] *= corr;
          #pragma unroll
          for (int nb = 0; nb < 8; ++nb) O[f][nb][r] = O[f][nb][r] * corr;
        }
      }
      #pragma unroll
      for (int r = 0; r < 4; ++r) {
        float psum = 0.f;
        #pragma unroll
        for (int sb = 0; sb < 4; ++sb) {
          float pp = __builtin_amdgcn_exp2f(S[sb][r] - m_r[f][r]);
          S[sb][r] = pp;
          psum += pp;
        }
        l_r[f][r] += psum;
      }
      #pragma unroll
      for (int sb = 0; sb < 4; ++sb) {
        int sl = sb * 16 + lj;
        int c = sl >> 3;
        #pragma unroll
        for (int r = 0; r < 4; ++r) {
          int rw = lg * 4 + r;
          Ps[w][(f * 16 + rw) * 64 + ((c ^ (rw & 7)) << 3) + (sl & 7)] = (__bf16)S[sb][r];
        }
      }
    }
    __syncthreads();
    __builtin_amdgcn_s_setprio(1);
    #pragma unroll
    for (int f = 0; f < 2; ++f) {
      if (f == 0 && !act0) continue;
      #pragma unroll
      for (int kk = 0; kk < 2; ++kk) {
        int ca = kk * 4 + lg;
        bf16x8 pa = *(const bf16x8*)&Ps[w][(f * 16 + lj) * 64 + ((ca ^ (lj & 7)) << 3)];
        #pragma unroll
        for (int nb = 0; nb < 8; ++nb) {
          int h = nb * 16 + lj;
          bf16x8 bv = *(const bf16x8*)&Vs[(ca * 128 + h) * 8];
          O[f][nb] = __builtin_amdgcn_mfma_f32_16x16x32_bf16(pa, bv, O[f][nb], 0, 0, 0);
        }
      }
    }
    __builtin_amdgcn_s_setprio(0);
    __syncthreads();
  }

  #pragma unroll
  for (int f = 0; f < 2; ++f) {
    const int qt = f ? qtf1 : qtf0;
    #pragma unroll
    for (int r = 0; r < 4; ++r) {
      float lsum = l_r[f][r];
      lsum += __shfl_xor(lsum, 1);
      lsum += __shfl_xor(lsum, 2);
      lsum += __shfl_xor(lsum, 4);
      lsum += __shfl_xor(lsum, 8);
      float inv = 1.0f / lsum;
      int t = qt * 64 + w * 16 + lg * 4 + r;
      __bf16* dst = attn_out + ((size_t)t * NH_ + n) * HV_;
      #pragma unroll
      for (int nb = 0; nb < 8; ++nb) dst[nb * 16 + lj] = (__bf16)(O[f][nb][r] * inv);
    }
  }
  #undef STAGE_K
  #undef STAGE_V
}

// ================= host side =================
static void compute_inv_freq(float* out) {
  const double theta = 10000.0, factor = 40.0;
  const double PI = 3.14159265358979323846;
  const int rot = ROPE_;
  double low_d  = rot * log(4096.0 / (32.0 * 2.0 * PI)) / (2.0 * log(theta));
  double high_d = rot * log(4096.0 / ( 1.0 * 2.0 * PI)) / (2.0 * log(theta));
  double low = floor(low_d);  if (low < 0) low = 0;
  double high = ceil(high_d); if (high > rot - 1) high = rot - 1;
  for (int i = 0; i < 32; ++i) {
    double pf = pow(theta, (2.0 * i) / (double)rot);
    double inv_extra = 1.0 / pf;
    double inv_inter = 1.0 / (factor * pf);
    double ramp = ((double)i - low) / fmax(high - low, 0.001);
    ramp = fmin(fmax(ramp, 0.0), 1.0);
    double mask = 1.0 - ramp;
    out[i] = (float)(inv_inter * (1.0 - mask) + inv_extra * mask);
  }
}

extern "C" void kernel_launch(void* const* d_in, const int* in_sizes, int n_in,
                              void* d_out, int out_size, void* d_ws, size_t ws_size,
                              hipStream_t stream) {
  const float* x            = (const float*)d_in[0];
  const int*   positions    = (const int*)d_in[1];
  const float* w_q_down     = (const float*)d_in[2];
  const float* q_norm_scale = (const float*)d_in[3];
  const float* w_q_up       = (const float*)d_in[4];
  const float* w_kv_down    = (const float*)d_in[5];
  const float* kv_norm_scale= (const float*)d_in[6];
  const float* w_kv_up      = (const float*)d_in[7];
  const float* w_o          = (const float*)d_in[8];
  float* out = (float*)d_out;

  // ---- workspace (float offsets); R14 layout ----
  float* ws = (float*)d_ws;
  float*  cosT     = ws;                           // live through q_up (fused rope)
  float*  sinT     = ws + 65536;
  __bf16* catb     = (__bf16*)(ws + 131072);       // T*2112 bf16; dead@rope_k
  __bf16* xb       = (__bf16*)(ws + 4456448);      // dead@down-gemm
  __bf16* Bt_cat   = (__bf16*)(ws + 8650752);      // dead@down-gemm
  __bf16* Bt_qu    = (__bf16*)(ws + 13107200);     // dead@qup-gemm
  __bf16* Bt_kvu   = (__bf16*)(ws + 17825792);     // dead@kvup-gemm
  __bf16* q_tab    = (__bf16*)(ws + 19922944);     // dead@qup-gemm
  __bf16* kv_latb  = (__bf16*)(ws + 21495808);     // dead@kvup-gemm
  __bf16* k_ropeb  = (__bf16*)(ws + 22020096);     // dead@attn
  __bf16* q_tnhb   = (__bf16*)(ws + 22085632);     // dead@attn
  __bf16* kv_nopeb = (__bf16*)(ws + 28377088);     // dead@attn
  // aliases (target regions dead before first write):
  __bf16* Vt       = (__bf16*)(ws + 13107200);     // over Bt_qu (dead after q_up)
  __bf16* attn_ob  = (__bf16*)(ws + 17825792);     // over Bt_kvu+q_tab+kv_latb
  __bf16* Bt_o     = (__bf16*)(ws + 4456448);      // over xb+Bt_cat
  (void)ws_size; (void)n_in; (void)in_sizes; (void)out_size;

  InvFreq invf;
  compute_inv_freq(invf.f);
  double ym = 0.1 * log(40.0) + 1.0;
  float sm_scale2 = (float)((ym * ym / sqrt((double)HQK_)) * 1.44269504088896340736);

  // tables + conversions + weight transposes
  rope_table_kernel<<<(T_ * 32 + 255) / 256, 256, 0, stream>>>(positions, cosT, sinT, invf);
  conv_bf16_kernel<<<T_ * D_ / 8 / 256, 256, 0, stream>>>(x, xb, T_ * D_ / 8);
  transpose_bf16_kernel<<<dim3(QL_ / 64, D_ / 64), 256, 0, stream>>>(w_q_down, Bt_cat, D_, QL_);
  transpose_bf16_kernel<<<dim3(KVD_ / 64, D_ / 64), 256, 0, stream>>>(w_kv_down, Bt_cat + (size_t)QL_ * D_, D_, KVD_);
  transpose_bf16_kernel<<<dim3(NH_ * HQK_ / 64, QL_ / 64), 256, 0, stream>>>(w_q_up, Bt_qu, QL_, NH_ * HQK_);
  transpose_bf16_kernel<<<dim3(NH_ * 256 / 64, KVL_ / 64), 256, 0, stream>>>(w_kv_up, Bt_kvu, KVL_, NH_ * 256);

  // fused down-projection (BK=128, async DMA staging — R14 form)
  mfma_gemm_bk128_kernel<__bf16><<<dim3((NCAT_ + 127) / 128, T_ / 128), 256, 0, stream>>>(xb, Bt_cat, catb, T_, NCAT_, D_);

  // q path (rope fused into q_up epilogue)
  rmsnorm_bf16_kernel<<<T_, 256, 0, stream>>>(catb, q_tab, q_norm_scale, QL_, NCAT_);
  qup_gemm_kernel<<<dim3(NH_ * HQK_ / 128, T_ / 128), 256, 0, stream>>>(q_tab, Bt_qu, q_tnhb, cosT, sinT, T_, NH_ * HQK_, QL_);

  // kv path: fused kv_up (nope -> kv_nopeb, V -> Vt transposed)
  rmsnorm_bf16_kernel<<<T_, 256, 0, stream>>>(catb + QL_, kv_latb, kv_norm_scale, KVL_, NCAT_);
  rope_k_kernel<<<(T_ * 32 + 255) / 256, 256, 0, stream>>>(catb + QL_ + KVL_, NCAT_, cosT, sinT, k_ropeb);
  kvup_gemm_kernel<<<dim3(NH_ * 2, T_ / 128), 256, 0, stream>>>(kv_latb, Bt_kvu, kv_nopeb, Vt);

  // attention (512 dual-q blocks, shared KV staging, XCD head-affinity)
  attn_mfma_kernel<<<512, 256, 0, stream>>>(q_tnhb, kv_nopeb, k_ropeb, Vt, attn_ob, sm_scale2);

  // output projection
  transpose_bf16_kernel<<<dim3(D_ / 64, NH_ * HV_ / 64), 256, 0, stream>>>(w_o, Bt_o, NH_ * HV_, D_);
  mfma_gemm_kernel<float><<<dim3(D_ / 128, T_ / 128), 256, 0, stream>>>(attn_ob, Bt_o, out, T_, D_, NH_ * HV_);
}